// Round 13
// baseline (1119.747 us; speedup 1.0000x reference)
//
#include <hip/hip_runtime.h>
#include <hip/hip_bf16.h>

#define NB 12

typedef __attribute__((ext_vector_type(8))) short bf16x8;
typedef __attribute__((ext_vector_type(4))) float f32x4;

#define MFMA16(a, b, c) __builtin_amdgcn_mfma_f32_16x16x32_bf16(a, b, c, 0, 0, 0)

__device__ __forceinline__ unsigned short bf16r(float f) {
  unsigned int u = __float_as_uint(f);
  return (unsigned short)((u + 0x7fffu + ((u >> 16) & 1u)) >> 16);
}

__device__ __forceinline__ float bf2f(unsigned short h) {
  return __uint_as_float(((unsigned int)h) << 16);
}

// order-preserving fp32 <-> u32 (for LDS atomicMin gate); works for +/-
__device__ __forceinline__ unsigned int fenc(float f) {
  unsigned int u = __float_as_uint(f);
  return (u >> 31) ? ~u : (u | 0x80000000u);
}
__device__ __forceinline__ float fdec(unsigned int e) {
  unsigned int u = (e >> 31) ? (e & 0x7FFFFFFFu) : ~e;
  return __uint_as_float(u);
}

__device__ __forceinline__ float4 relu4(float4 v) {
  v.x = fmaxf(v.x, 0.f); v.y = fmaxf(v.y, 0.f);
  v.z = fmaxf(v.z, 0.f); v.w = fmaxf(v.w, 0.f);
  return v;
}

// packed RNE f32x2 -> bf16x2 (v_cvt_pk_bf16_f32)
__device__ __forceinline__ unsigned int pkbf(float x, float y) {
  __hip_bfloat162 h = __float22bfloat162_rn(make_float2(x, y));
  return *reinterpret_cast<unsigned int*>(&h);
}

// split fp32 pair-of-float4 into hi/lo bf16x8 via cvt_pk (hi=RNE, lo=RNE(residual))
__device__ __forceinline__ void split8(float4 a, float4 b, bf16x8* ph, bf16x8* pl) {
  unsigned int h01 = pkbf(a.x, a.y), h23 = pkbf(a.z, a.w);
  unsigned int h45 = pkbf(b.x, b.y), h67 = pkbf(b.z, b.w);
  float r0 = a.x - __uint_as_float(h01 << 16);
  float r1 = a.y - __uint_as_float(h01 & 0xFFFF0000u);
  float r2 = a.z - __uint_as_float(h23 << 16);
  float r3 = a.w - __uint_as_float(h23 & 0xFFFF0000u);
  float r4 = b.x - __uint_as_float(h45 << 16);
  float r5 = b.y - __uint_as_float(h45 & 0xFFFF0000u);
  float r6 = b.z - __uint_as_float(h67 << 16);
  float r7 = b.w - __uint_as_float(h67 & 0xFFFF0000u);
  uint4 H = make_uint4(h01, h23, h45, h67);
  uint4 L = make_uint4(pkbf(r0, r1), pkbf(r2, r3), pkbf(r4, r5), pkbf(r6, r7));
  *ph = *reinterpret_cast<bf16x8*>(&H);
  *pl = *reinterpret_cast<bf16x8*>(&L);
}

// xyz (b,3,n) -> x (b,n,3)
__global__ __launch_bounds__(256) void k_transpose_in(
    const float* __restrict__ xyz, float* __restrict__ x, int n) {
  int gid = blockIdx.x * 256 + threadIdx.x;
  if (gid >= 4 * n) return;
  int b = gid / n, i = gid % n;
  const float* src = xyz + (size_t)b * 3 * n;
  float* dst = x + (size_t)gid * 3;
  dst[0] = src[i];
  dst[1] = src[n + i];
  dst[2] = src[2 * n + i];
}

// weight prep hi/lo via LDS tile transpose (coalesced both sides):
// wt[i][e][d] = d<128 ? wc[i][d][e] : wn[i][d-128][e].
__global__ __launch_bounds__(256) void k_wt(
    const float* __restrict__ wc, const float* __restrict__ wn,
    unsigned short* __restrict__ wth, unsigned short* __restrict__ wtl) {
  __shared__ float tile[32][33];
  int bid = blockIdx.x;
  int et = bid & 3, dt = (bid >> 2) & 7, i = bid >> 5;
  int d0 = dt * 32, e0 = et * 32;
  int t = threadIdx.x;
  int el = t & 31, dg = t >> 5;
  const float* src = (d0 < 128) ? (wc + (size_t)i * 16384 + (size_t)d0 * 128)
                                : (wn + (size_t)i * 16384 + (size_t)(d0 - 128) * 128);
#pragma unroll
  for (int u = 0; u < 4; u++) {
    int dl = dg * 4 + u;
    tile[dl][el] = src[(size_t)dl * 128 + e0 + el];
  }
  __syncthreads();
  int dl = t & 31, eg = t >> 5;
#pragma unroll
  for (int u = 0; u < 4; u++) {
    int el2 = eg * 4 + u;
    float v = tile[dl][el2];
    unsigned short h = bf16r(v);
    size_t o = (size_t)i * 32768 + (size_t)(e0 + el2) * 256 + d0 + dl;
    wth[o] = h;
    wtl[o] = bf16r(v - bf2f(h));
  }
}

// featnet weight prep: wt[e][d] = w[d][e] hi/lo (w is [128][128])
__global__ __launch_bounds__(256) void k_wtf(
    const float* __restrict__ w, unsigned short* __restrict__ wh,
    unsigned short* __restrict__ wl) {
  int tid = blockIdx.x * 256 + threadIdx.x;  // 16384
  int e = tid >> 7, d = tid & 127;
  float v = w[d * 128 + e];
  unsigned short h = bf16r(v);
  wh[tid] = h;
  wl[tid] = bf16r(v - bf2f(h));
}

// A-fragment prep for MFMA kNN: per 16-ref tile, per lane (ref=lane&15, kg=lane>>4)
// K-slot layout (K=32): k0..2=Rh, k3..5=Rl, k6..8=Rh, k9=rrh, k10=rrl, rest 0.
__global__ __launch_bounds__(256) void k_frag(
    const float* __restrict__ pts, unsigned short* __restrict__ frag, int n) {
  int gid = blockIdx.x * 256 + threadIdx.x;
  int ntiles = n >> 4;
  if (gid >= 4 * ntiles * 64) return;
  int lane = gid & 63;
  int bt = gid >> 6;
  int b = bt / ntiles, tile = bt % ntiles;
  int rin = lane & 15, kg = lane >> 4;
  const float* p = pts + ((size_t)b * n + tile * 16 + rin) * 3;
  float px = p[0], py = p[1], pz = p[2];
  float rr = px * px + py * py + pz * pz;
  unsigned short h0 = bf16r(px), h1 = bf16r(py), h2 = bf16r(pz);
  unsigned short l0 = bf16r(px - bf2f(h0));
  unsigned short l1 = bf16r(py - bf2f(h1));
  unsigned short l2 = bf16r(pz - bf2f(h2));
  unsigned short rh = bf16r(rr), rl = bf16r(rr - bf2f(rh));
  bf16x8 f = (bf16x8)0;
  if (kg == 0) {
    f[0] = (short)h0; f[1] = (short)h1; f[2] = (short)h2;
    f[3] = (short)l0; f[4] = (short)l1; f[5] = (short)l2;
    f[6] = (short)h0; f[7] = (short)h1;
  } else if (kg == 1) {
    f[0] = (short)h2; f[1] = (short)rh; f[2] = (short)rl;
  }
  *(bf16x8*)(frag + (size_t)gid * 8) = f;
}

#define LCAS(A, B)                                                        \
  {                                                                       \
    bool sw_ = (dist[B] < dist[A]) ||                                     \
               (dist[B] == dist[A] && ind[B] < ind[A]);                   \
    float td_ = sw_ ? dist[A] : dist[B];                                  \
    int ti_ = sw_ ? ind[A] : ind[B];                                      \
    dist[A] = sw_ ? dist[B] : dist[A];                                    \
    ind[A] = sw_ ? ind[B] : ind[A];                                      \
    dist[B] = td_; ind[B] = ti_;                                          \
  }

// MFMA kNN, two-stage, 2-way ref split, SHARED cross-wave gate.
// Gate refreshed every 4 tiles (fires concentrate early while gate stale).
__global__ __launch_bounds__(256) void k_knn2(
    const float* __restrict__ Q, const float* __restrict__ Rpts,
    const unsigned short* __restrict__ frag,
    int* __restrict__ idx, int M, int N) {
  __shared__ unsigned short chunkbuf[32 * 512];  // 32 tiles * 1024 B = 32 KB
  __shared__ float smd[4][16][8];
  __shared__ int smi[4][16][8];
  __shared__ unsigned int qgate[32];
  int b = blockIdx.y;
  int t = threadIdx.x;
  int w = t >> 6, lane = t & 63;
  int col = lane & 15, kg = lane >> 4;
  int qg = w & 1, zh = w >> 1;
  int q = blockIdx.x * 32 + qg * 16 + col;
  if (t < 32) qgate[t] = fenc(3.4e38f);
  const float* qp = Q + ((size_t)b * M + q) * 3;
  float qx = qp[0], qy = qp[1], qz = qp[2];
  float qq = qx * qx + qy * qy + qz * qz;
  float m2x = -2.f * qx, m2y = -2.f * qy, m2z = -2.f * qz;
  unsigned short h0 = bf16r(m2x), h1 = bf16r(m2y), h2 = bf16r(m2z);
  unsigned short l0 = bf16r(m2x - bf2f(h0));
  unsigned short l1 = bf16r(m2y - bf2f(h1));
  unsigned short l2 = bf16r(m2z - bf2f(h2));
  bf16x8 bfrag = (bf16x8)0;
  if (kg == 0) {
    bfrag[0] = (short)h0; bfrag[1] = (short)h1; bfrag[2] = (short)h2;
    bfrag[3] = (short)h0; bfrag[4] = (short)h1; bfrag[5] = (short)h2;
    bfrag[6] = (short)l0; bfrag[7] = (short)l1;
  } else if (kg == 1) {
    bfrag[0] = (short)l2;
    bfrag[1] = (short)0x3F80; bfrag[2] = (short)0x3F80;  // 1.0 bf16
  }
  float dist[8];
  int ind[8];
#pragma unroll
  for (int j = 0; j < 8; j++) { dist[j] = 3.4e38f; ind[j] = 0; }
  float g8 = 3.4e38f;  // shared-gate snapshot (stale = looser = safe)
  int ntiles = N >> 4;
  int half = ntiles >> 1;
  const unsigned short* fb = frag + (size_t)b * ntiles * 512;
  for (int c = 0; c < half; c += 16) {
    __syncthreads();
    {
      const float4* src = (const float4*)fb;
      float4* dst = (float4*)chunkbuf;
      for (int i = t; i < 1024; i += 256) {
        dst[i] = src[(size_t)c * 64 + i];
        dst[1024 + i] = src[(size_t)(half + c) * 64 + i];
      }
    }
    __syncthreads();
    int lbase = zh * 16;
    int cbase = (zh * half + c) * 16;
    for (int tl = 0; tl < 16; tl++) {
      bf16x8 af = *(const bf16x8*)(&chunkbuf[((lbase + tl) * 64 + lane) * 8]);
      f32x4 z = (f32x4){0.f, 0.f, 0.f, 0.f};
      f32x4 sc = MFMA16(af, bfrag, z);
      float g = fminf(dist[7], g8);
      unsigned int m = 0;
      m |= (sc[0] < g) ? 1u : 0u;
      m |= (sc[1] < g) ? 2u : 0u;
      m |= (sc[2] < g) ? 4u : 0u;
      m |= (sc[3] < g) ? 8u : 0u;
#pragma unroll 1
      for (int it = 0; it < 4; ++it) {
        if (!__any(m != 0u)) break;
        if (m != 0u) {
          int r = (int)__builtin_ctz(m);
          m &= m - 1u;
          float dd = (r & 2) ? ((r & 1) ? sc[3] : sc[2])
                             : ((r & 1) ? sc[1] : sc[0]);
          int ii = cbase + tl * 16 + kg * 4 + r;
#pragma unroll
          for (int j = 0; j < 8; j++) {  // bubble insert; self-guards if dd >= dist[7]
            bool sw = dd < dist[j];
            float td = sw ? dist[j] : dd;
            int ti = sw ? ind[j] : ii;
            dist[j] = sw ? dd : dist[j];
            ind[j] = sw ? ii : ind[j];
            dd = td; ii = ti;
          }
        }
      }
      if ((tl & 3) == 3) {  // refresh shared gate every 4 tiles
        float t1 = fminf(dist[7], __shfl_xor(dist[7], 16, 64));
        float own8 = fminf(t1, __shfl_xor(t1, 32, 64));
        if (kg == 0) atomicMin(&qgate[qg * 16 + col], fenc(own8));
        g8 = fminf(own8, fdec(qgate[qg * 16 + col]));
      }
    }
  }
  // exact fp32 rescore of this lane's 8 candidates + stable lex resort
  {
    const float* Rb2 = Rpts + (size_t)b * N * 3;
    float nd[8];
#pragma unroll
    for (int j = 0; j < 8; j++) {
      int ii = ind[j];
      float rx = Rb2[(size_t)ii * 3 + 0];
      float ry = Rb2[(size_t)ii * 3 + 1];
      float rz = Rb2[(size_t)ii * 3 + 2];
      float rr = rx * rx + ry * ry + rz * rz;
      nd[j] = qq + rr - 2.0f * (qx * rx + qy * ry + qz * rz);
    }
    float sd[8]; int si[8];
#pragma unroll
    for (int j = 0; j < 8; j++) { sd[j] = 3.4e38f; si[j] = 0x7fffffff; }
#pragma unroll
    for (int j = 0; j < 8; j++) {
      float dd = nd[j]; int ii = ind[j];
#pragma unroll
      for (int p = 0; p < 8; p++) {
        bool sw = (dd < sd[p]) || (dd == sd[p] && ii < si[p]);
        float td = sw ? sd[p] : dd;
        int ti = sw ? si[p] : ii;
        sd[p] = sw ? dd : sd[p];
        si[p] = sw ? ii : si[p];
        dd = td; ii = ti;
      }
    }
#pragma unroll
    for (int j = 0; j < 8; j++) { dist[j] = sd[j]; ind[j] = si[j]; }
  }
  // merge 4 sorted kg-lists of each query: levels xor 16, 32
#pragma unroll
  for (int lev = 0; lev < 2; lev++) {
    int D = 16 << lev;
    float od[8]; int oi[8];
#pragma unroll
    for (int j = 0; j < 8; j++) {
      od[j] = __shfl_xor(dist[j], D, 64);
      oi[j] = __shfl_xor(ind[j], D, 64);
    }
#pragma unroll
    for (int j = 0; j < 8; j++) {  // half-cleaner: keep 8 smallest (lex)
      float bd = od[7 - j]; int bi = oi[7 - j];
      bool take = (bd < dist[j]) || (bd == dist[j] && bi < ind[j]);
      dist[j] = take ? bd : dist[j];
      ind[j] = take ? bi : ind[j];
    }
    LCAS(0, 4) LCAS(1, 5) LCAS(2, 6) LCAS(3, 7)
    LCAS(0, 2) LCAS(1, 3) LCAS(4, 6) LCAS(5, 7)
    LCAS(0, 1) LCAS(2, 3) LCAS(4, 5) LCAS(6, 7)
  }
  if (kg == 0) {
#pragma unroll
    for (int j = 0; j < 8; j++) { smd[w][col][j] = dist[j]; smi[w][col][j] = ind[j]; }
  }
  __syncthreads();
  // cross-half rank merge: thread (tq, jj); query group g = tq>>4 -> lists g, g+2
  int tq = t >> 3, jj = t & 7;
  int g = tq >> 4, qcol = tq & 15;
  float d0 = smd[g][qcol][jj];     int i0 = smi[g][qcol][jj];
  float d1 = smd[g + 2][qcol][jj]; int i1 = smi[g + 2][qcol][jj];
  int r0 = jj, r1 = jj;
#pragma unroll
  for (int p = 0; p < 8; p++) {
    float dp = smd[g + 2][qcol][p]; int ip = smi[g + 2][qcol][p];
    r0 += (dp < d0 || (dp == d0 && ip < i0)) ? 1 : 0;
    float dq = smd[g][qcol][p];     int iq = smi[g][qcol][p];
    r1 += (dq < d1 || (dq == d1 && iq < i1)) ? 1 : 0;
  }
  int* o = idx + ((size_t)b * M + blockIdx.x * 32 + tq) * 8;
  if (r0 < 8) o[r0] = i0;
  if (r1 < 8) o[r1] = i1;
}

// feature_net via split-bf16 MFMA: 8 queries/block -> 64 rows (q*8+j).
__global__ __launch_bounds__(256) void k_featnet2(
    const float* __restrict__ x, const int* __restrict__ idx,
    const float* __restrict__ w0,
    const unsigned short* __restrict__ w1h, const unsigned short* __restrict__ w1l,
    const unsigned short* __restrict__ w2h, const unsigned short* __restrict__ w2l,
    float* __restrict__ out, int n) {
  __shared__ unsigned short Xh[64 * 128];  // 16 KB
  __shared__ unsigned short Xl[64 * 128];  // 16 KB
  __shared__ float F[64 * 128];            // 32 KB
  int b = blockIdx.y, t = threadIdx.x;
  int q0 = blockIdx.x * 8;
  {
    int row = t >> 2, seg = t & 3;
    int qi = row >> 3, j = row & 7;
    size_t qb = (size_t)b * n + q0 + qi;
    const float* qp = x + qb * 3;
    int nb = idx[qb * 8 + j];
    const float* pp = x + ((size_t)b * n + nb) * 3;
    float r0 = pp[0] - qp[0], r1 = pp[1] - qp[1], r2 = pp[2] - qp[2];
#pragma unroll
    for (int u = 0; u < 4; u++) {
      int cc = seg * 32 + u * 8;
      float h[8];
#pragma unroll
      for (int v = 0; v < 8; v++) {
        int c = cc + v;
        h[v] = fmaxf(fmaf(r0, w0[c], fmaf(r1, w0[128 + c], r2 * w0[256 + c])), 0.f);
      }
      float4 a = make_float4(h[0], h[1], h[2], h[3]);
      float4 bb = make_float4(h[4], h[5], h[6], h[7]);
      int lc = seg * 4 + u;
      int ph = row * 128 + ((lc ^ (row & 7)) * 8);
      split8(a, bb, (bf16x8*)&Xh[ph], (bf16x8*)&Xl[ph]);
    }
  }
  __syncthreads();
  int w = t >> 6, lane = t & 63;
  int lo = lane & 15, hi = lane >> 4;
  f32x4 acc[4][2];
#pragma unroll
  for (int mt = 0; mt < 4; mt++)
#pragma unroll
    for (int nt = 0; nt < 2; nt++) acc[mt][nt] = (f32x4){0.f, 0.f, 0.f, 0.f};
  {
    const unsigned short* wbh = w1h + ((size_t)(w * 32 + lo) * 128 + hi * 8);
    const unsigned short* wbl = w1l + ((size_t)(w * 32 + lo) * 128 + hi * 8);
#pragma unroll
    for (int kk = 0; kk < 4; kk++) {
      bf16x8 ah[4], al[4];
#pragma unroll
      for (int mt = 0; mt < 4; mt++) {
        int row = mt * 16 + lo;
        int off = row * 128 + (((4 * kk + hi) ^ (row & 7)) * 8);
        ah[mt] = *(const bf16x8*)(&Xh[off]);
        al[mt] = *(const bf16x8*)(&Xl[off]);
      }
      bf16x8 bh0 = *(const bf16x8*)(wbh + kk * 32);
      bf16x8 bh1 = *(const bf16x8*)(wbh + 16 * 128 + kk * 32);
      bf16x8 bl0 = *(const bf16x8*)(wbl + kk * 32);
      bf16x8 bl1 = *(const bf16x8*)(wbl + 16 * 128 + kk * 32);
#pragma unroll
      for (int mt = 0; mt < 4; mt++) {
        acc[mt][0] = MFMA16(ah[mt], bh0, acc[mt][0]);
        acc[mt][0] = MFMA16(ah[mt], bl0, acc[mt][0]);
        acc[mt][0] = MFMA16(al[mt], bh0, acc[mt][0]);
        acc[mt][1] = MFMA16(ah[mt], bh1, acc[mt][1]);
        acc[mt][1] = MFMA16(ah[mt], bl1, acc[mt][1]);
        acc[mt][1] = MFMA16(al[mt], bh1, acc[mt][1]);
      }
    }
  }
#pragma unroll
  for (int mt = 0; mt < 4; mt++)
#pragma unroll
    for (int nt = 0; nt < 2; nt++) {
      int colc = w * 32 + nt * 16 + lo;
      int chunk = colc >> 2, cr = colc & 3;
#pragma unroll
      for (int r = 0; r < 4; r++) {
        int row = mt * 16 + hi * 4 + r;
        F[row * 128 + ((chunk ^ ((row & 7) << 2)) << 2) + cr] = acc[mt][nt][r];
      }
    }
  __syncthreads();
  {
    int row = t >> 2, seg = t & 3;
#pragma unroll
    for (int u = 0; u < 4; u++) {
      int cc = (seg * 32 + u * 8) >> 2;  // even chunk index
      int pc = cc ^ ((row & 7) << 2);
      float4 a = *(const float4*)(&F[row * 128 + pc * 4]);
      float4 bb = *(const float4*)(&F[row * 128 + (pc + 1) * 4]);
      a = relu4(a); bb = relu4(bb);
      int lc = seg * 4 + u;
      int ph = row * 128 + ((lc ^ (row & 7)) * 8);
      split8(a, bb, (bf16x8*)&Xh[ph], (bf16x8*)&Xl[ph]);
    }
  }
  __syncthreads();
#pragma unroll
  for (int mt = 0; mt < 4; mt++)
#pragma unroll
    for (int nt = 0; nt < 2; nt++) acc[mt][nt] = (f32x4){0.f, 0.f, 0.f, 0.f};
  {
    const unsigned short* wbh = w2h + ((size_t)(w * 32 + lo) * 128 + hi * 8);
    const unsigned short* wbl = w2l + ((size_t)(w * 32 + lo) * 128 + hi * 8);
#pragma unroll
    for (int kk = 0; kk < 4; kk++) {
      bf16x8 ah[4], al[4];
#pragma unroll
      for (int mt = 0; mt < 4; mt++) {
        int row = mt * 16 + lo;
        int off = row * 128 + (((4 * kk + hi) ^ (row & 7)) * 8);
        ah[mt] = *(const bf16x8*)(&Xh[off]);
        al[mt] = *(const bf16x8*)(&Xl[off]);
      }
      bf16x8 bh0 = *(const bf16x8*)(wbh + kk * 32);
      bf16x8 bh1 = *(const bf16x8*)(wbh + 16 * 128 + kk * 32);
      bf16x8 bl0 = *(const bf16x8*)(wbl + kk * 32);
      bf16x8 bl1 = *(const bf16x8*)(wbl + 16 * 128 + kk * 32);
#pragma unroll
      for (int mt = 0; mt < 4; mt++) {
        acc[mt][0] = MFMA16(ah[mt], bh0, acc[mt][0]);
        acc[mt][0] = MFMA16(ah[mt], bl0, acc[mt][0]);
        acc[mt][0] = MFMA16(al[mt], bh0, acc[mt][0]);
        acc[mt][1] = MFMA16(ah[mt], bh1, acc[mt][1]);
        acc[mt][1] = MFMA16(ah[mt], bl1, acc[mt][1]);
        acc[mt][1] = MFMA16(al[mt], bh1, acc[mt][1]);
      }
    }
  }
#pragma unroll
  for (int mt = 0; mt < 4; mt++)
#pragma unroll
    for (int nt = 0; nt < 2; nt++) {
      float m = fmaxf(fmaxf(acc[mt][nt][0], acc[mt][nt][1]),
                      fmaxf(acc[mt][nt][2], acc[mt][nt][3]));
      float o = fmaxf(m, __shfl_xor(m, 16, 64));
      if ((hi & 1) == 0) {
        int q = q0 + mt * 2 + (hi >> 1);
        out[((size_t)b * n + q) * 128 + w * 32 + nt * 16 + lo] = fmaxf(o, 0.f);
      }
    }
}

// residual graph-conv, BM=32 (used at n1), XCD-bound 1D grid.
__global__ __launch_bounds__(256) void k_conv(
    const float* __restrict__ Pin, float* __restrict__ Pout,
    const int* __restrict__ idx, const unsigned short* __restrict__ wth,
    const unsigned short* __restrict__ wtl, int n) {
  __shared__ unsigned short Xh[32 * 256];  // 16 KB
  __shared__ unsigned short Xl[32 * 256];  // 16 KB
  int t = threadIdx.x;
  int fid = blockIdx.x;
  int x8 = fid & 7;
  int b = x8 >> 1;
  int rblk = ((fid >> 3) * 2 + (x8 & 1)) * 32;
  {
    int row = t >> 3, seg = t & 7;
    size_t rb = (size_t)b * n + rblk + row;
    const float4* src = (const float4*)(Pin + rb * 128 + seg * 16);
    float4 cv[4];
#pragma unroll
    for (int u = 0; u < 4; u++) cv[u] = relu4(src[u]);
    const int* ip = idx + rb * 8;
    float4 ns[4];
#pragma unroll
    for (int u = 0; u < 4; u++) ns[u] = make_float4(0.f, 0.f, 0.f, 0.f);
#pragma unroll
    for (int j = 0; j < 8; j++) {
      const float4* s2 = (const float4*)(Pin + ((size_t)b * n + ip[j]) * 128 + seg * 16);
#pragma unroll
      for (int u = 0; u < 4; u++) {
        float4 v = relu4(s2[u]);
        ns[u].x += v.x; ns[u].y += v.y; ns[u].z += v.z; ns[u].w += v.w;
      }
    }
#pragma unroll
    for (int u = 0; u < 2; u++) {
      int lc = seg * 2 + u;
      int ph = (row * 256 + ((lc ^ (row & 7)) * 8));
      split8(cv[2 * u], cv[2 * u + 1], (bf16x8*)&Xh[ph], (bf16x8*)&Xl[ph]);
      int lc2 = 16 + seg * 2 + u;
      int ph2 = (row * 256 + ((lc2 ^ (row & 7)) * 8));
      split8(ns[2 * u], ns[2 * u + 1], (bf16x8*)&Xh[ph2], (bf16x8*)&Xl[ph2]);
    }
  }
  __syncthreads();
  int w = t >> 6, lane = t & 63;
  int lo = lane & 15, hi = lane >> 4;
  f32x4 acc[2][2];
#pragma unroll
  for (int mt = 0; mt < 2; mt++)
#pragma unroll
    for (int nt = 0; nt < 2; nt++) acc[mt][nt] = (f32x4){0.f, 0.f, 0.f, 0.f};
  const unsigned short* wbh = wth + ((size_t)(w * 32 + lo) * 256 + hi * 8);
  const unsigned short* wbl = wtl + ((size_t)(w * 32 + lo) * 256 + hi * 8);
#pragma unroll
  for (int kk = 0; kk < 8; kk++) {
    bf16x8 ah[2], al[2];
#pragma unroll
    for (int mt = 0; mt < 2; mt++) {
      int row = mt * 16 + lo;
      int off = row * 256 + (((4 * kk + hi) ^ (row & 7)) * 8);
      ah[mt] = *(const bf16x8*)(&Xh[off]);
      al[mt] = *(const bf16x8*)(&Xl[off]);
    }
    bf16x8 bh0 = *(const bf16x8*)(wbh + kk * 32);
    bf16x8 bh1 = *(const bf16x8*)(wbh + 4096 + kk * 32);
    bf16x8 bl0 = *(const bf16x8*)(wbl + kk * 32);
    bf16x8 bl1 = *(const bf16x8*)(wbl + 4096 + kk * 32);
#pragma unroll
    for (int mt = 0; mt < 2; mt++) {
      acc[mt][0] = MFMA16(ah[mt], bh0, acc[mt][0]);
      acc[mt][0] = MFMA16(ah[mt], bl0, acc[mt][0]);
      acc[mt][0] = MFMA16(al[mt], bh0, acc[mt][0]);
      acc[mt][1] = MFMA16(ah[mt], bh1, acc[mt][1]);
      acc[mt][1] = MFMA16(ah[mt], bl1, acc[mt][1]);
      acc[mt][1] = MFMA16(al[mt], bh1, acc[mt][1]);
    }
  }
  const float inv9 = 1.0f / 9.0f;
#pragma unroll
  for (int mt = 0; mt < 2; mt++)
#pragma unroll
    for (int nt = 0; nt < 2; nt++) {
      int col = w * 32 + nt * 16 + lo;
#pragma unroll
      for (int r = 0; r < 4; r++) {
        int row = rblk + mt * 16 + hi * 4 + r;
        size_t off = ((size_t)b * n + row) * 128 + col;
        Pout[off] = fmaf(acc[mt][nt][r], inv9, Pin[off]);
      }
    }
}

// residual graph-conv, BM=64 (used at n2): halves per-dispatch weight traffic
// (weights loaded once per kk for 4 row-tiles). R4-verified staging/indexing.
__global__ __launch_bounds__(256) void k_conv64(
    const float* __restrict__ Pin, float* __restrict__ Pout,
    const int* __restrict__ idx, const unsigned short* __restrict__ wth,
    const unsigned short* __restrict__ wtl, int n) {
  __shared__ unsigned short Xh[64 * 256];  // 32 KB
  __shared__ unsigned short Xl[64 * 256];  // 32 KB
  int t = threadIdx.x;
  int fid = blockIdx.x;
  int x8 = fid & 7;
  int b = x8 >> 1;
  int rblk = ((fid >> 3) * 2 + (x8 & 1)) * 64;
  {
    int row = t >> 2, seg = t & 3;
    size_t rb = (size_t)b * n + rblk + row;
    const float4* src = (const float4*)(Pin + rb * 128 + seg * 32);
    float4 cv[8];
#pragma unroll
    for (int u = 0; u < 8; u++) cv[u] = relu4(src[u]);
    const int* ip = idx + rb * 8;
    float4 ns[8];
#pragma unroll
    for (int u = 0; u < 8; u++) ns[u] = make_float4(0.f, 0.f, 0.f, 0.f);
#pragma unroll
    for (int j = 0; j < 8; j++) {
      const float4* s2 = (const float4*)(Pin + ((size_t)b * n + ip[j]) * 128 + seg * 32);
#pragma unroll
      for (int u = 0; u < 8; u++) {
        float4 v = relu4(s2[u]);
        ns[u].x += v.x; ns[u].y += v.y; ns[u].z += v.z; ns[u].w += v.w;
      }
    }
#pragma unroll
    for (int u = 0; u < 4; u++) {
      int lc = seg * 4 + u;                         // center chunks 0..15
      int ph = (row * 256 + ((lc ^ (row & 7)) * 8));
      split8(cv[2 * u], cv[2 * u + 1], (bf16x8*)&Xh[ph], (bf16x8*)&Xl[ph]);
      int lc2 = 16 + seg * 4 + u;                   // neighbor-sum chunks 16..31
      int ph2 = (row * 256 + ((lc2 ^ (row & 7)) * 8));
      split8(ns[2 * u], ns[2 * u + 1], (bf16x8*)&Xh[ph2], (bf16x8*)&Xl[ph2]);
    }
  }
  __syncthreads();
  int w = t >> 6, lane = t & 63;
  int lo = lane & 15, hi = lane >> 4;
  f32x4 acc[4][2];
#pragma unroll
  for (int mt = 0; mt < 4; mt++)
#pragma unroll
    for (int nt = 0; nt < 2; nt++) acc[mt][nt] = (f32x4){0.f, 0.f, 0.f, 0.f};
  const unsigned short* wbh = wth + ((size_t)(w * 32 + lo) * 256 + hi * 8);
  const unsigned short* wbl = wtl + ((size_t)(w * 32 + lo) * 256 + hi * 8);
#pragma unroll
  for (int kk = 0; kk < 8; kk++) {
    bf16x8 bh0 = *(const bf16x8*)(wbh + kk * 32);
    bf16x8 bh1 = *(const bf16x8*)(wbh + 4096 + kk * 32);
    bf16x8 bl0 = *(const bf16x8*)(wbl + kk * 32);
    bf16x8 bl1 = *(const bf16x8*)(wbl + 4096 + kk * 32);
#pragma unroll
    for (int mt = 0; mt < 4; mt++) {
      int row = mt * 16 + lo;
      int off = row * 256 + (((4 * kk + hi) ^ (row & 7)) * 8);
      bf16x8 ah = *(const bf16x8*)(&Xh[off]);
      bf16x8 al = *(const bf16x8*)(&Xl[off]);
      acc[mt][0] = MFMA16(ah, bh0, acc[mt][0]);
      acc[mt][0] = MFMA16(ah, bl0, acc[mt][0]);
      acc[mt][0] = MFMA16(al, bh0, acc[mt][0]);
      acc[mt][1] = MFMA16(ah, bh1, acc[mt][1]);
      acc[mt][1] = MFMA16(ah, bl1, acc[mt][1]);
      acc[mt][1] = MFMA16(al, bh1, acc[mt][1]);
    }
  }
  const float inv9 = 1.0f / 9.0f;
#pragma unroll
  for (int mt = 0; mt < 4; mt++)
#pragma unroll
    for (int nt = 0; nt < 2; nt++) {
      int col = w * 32 + nt * 16 + lo;
#pragma unroll
      for (int r = 0; r < 4; r++) {
        int row = rblk + mt * 16 + hi * 4 + r;
        size_t off = ((size_t)b * n + row) * 128 + col;
        Pout[off] = fmaf(acc[mt][nt][r], inv9, Pin[off]);
      }
    }
}

// unpool: off6 = (relu(P)@uc + ns@un)/9; new[b][r*n+i][j] = xin[b][i][j] + off6[j*2+r]
__global__ __launch_bounds__(256) void k_unpool(
    const float* __restrict__ Pin, const int* __restrict__ idx,
    const float* __restrict__ xin,
    const float* __restrict__ uc, const float* __restrict__ un,
    float* __restrict__ out, int n, int transposed) {
  int b = blockIdx.y;
  int wv = threadIdx.x >> 6, lane = threadIdx.x & 63;
  int i = blockIdx.x * 4 + wv;
  if (i >= n) return;
  size_t rb = (size_t)b * n + i;
  const float* p0 = Pin + rb * 128;
  float pd0 = fmaxf(p0[lane], 0.f), pd1 = fmaxf(p0[lane + 64], 0.f);
  const int* ip = idx + rb * 8;
  float ns0 = 0.f, ns1 = 0.f;
#pragma unroll
  for (int j = 0; j < 8; j++) {
    const float* pj = Pin + ((size_t)b * n + ip[j]) * 128;
    ns0 += fmaxf(pj[lane], 0.f);
    ns1 += fmaxf(pj[lane + 64], 0.f);
  }
  float acc[6];
#pragma unroll
  for (int o = 0; o < 6; o++)
    acc[o] = pd0 * uc[lane * 6 + o] + pd1 * uc[(lane + 64) * 6 + o] +
             ns0 * un[lane * 6 + o] + ns1 * un[(lane + 64) * 6 + o];
#pragma unroll
  for (int s = 32; s > 0; s >>= 1) {
#pragma unroll
    for (int o = 0; o < 6; o++) acc[o] += __shfl_xor(acc[o], s, 64);
  }
  if (lane < 6) {
    int j = lane >> 1, r = lane & 1;
    float v = xin[rb * 3 + j] + acc[lane] * (1.0f / 9.0f);
    if (transposed)
      out[(size_t)b * 6 * n + (size_t)j * 2 * n + (size_t)r * n + i] = v;
    else
      out[((size_t)b * 2 * n + (size_t)r * n + i) * 3 + j] = v;
  }
}

// points2[b][m] = mean_j Pin[b][idx[b][m][j]]
__global__ __launch_bounds__(256) void k_meangather(
    const float* __restrict__ Pin, const int* __restrict__ idx,
    float* __restrict__ Pout, int M, int nsrc) {
  int gid = blockIdx.x * 256 + threadIdx.x;
  int row = gid >> 6, lane = gid & 63;
  if (row >= 4 * M) return;
  int b = row / M;
  const int* ip = idx + (size_t)row * 8;
  float s0 = 0.f, s1 = 0.f;
#pragma unroll
  for (int j = 0; j < 8; j++) {
    const float* p = Pin + ((size_t)b * nsrc + ip[j]) * 128;
    s0 += p[lane];
    s1 += p[lane + 64];
  }
  Pout[(size_t)row * 128 + lane] = s0 * 0.125f;
  Pout[(size_t)row * 128 + lane + 64] = s1 * 0.125f;
}

extern "C" void kernel_launch(void* const* d_in, const int* in_sizes, int n_in,
                              void* d_out, int out_size, void* d_ws, size_t ws_size,
                              hipStream_t stream) {
  const float* xyz = (const float*)d_in[0];
  const float* fw0 = (const float*)d_in[1];
  const float* fw1 = (const float*)d_in[2];
  const float* fw2 = (const float*)d_in[3];
  const float* u1wc = (const float*)d_in[4];
  const float* u1wn = (const float*)d_in[5];
  const float* u1uc = (const float*)d_in[6];
  const float* u1un = (const float*)d_in[7];
  const float* u2wc = (const float*)d_in[8];
  const float* u2wn = (const float*)d_in[9];
  const float* u2uc = (const float*)d_in[10];
  const float* u2un = (const float*)d_in[11];
  float* out = (float*)d_out;

  const int n1 = 4096, n2 = 8192, B = 4;
  float* ws = (float*)d_ws;
  float* x = ws;                                  // B*n1*3
  float* nxz = x + (size_t)B * n1 * 3;            // B*n2*3
  int* idx1 = (int*)(nxz + (size_t)B * n2 * 3);   // B*n1*8
  int* idx2g = idx1 + (size_t)B * n1 * 8;         // B*n2*8
  int* idx2s = idx2g + (size_t)B * n2 * 8;        // B*n2*8
  float* A = (float*)(idx2s + (size_t)B * n2 * 8);
  float* Bb = A + (size_t)B * n2 * 128;
  unsigned short* wt1h = (unsigned short*)(Bb + (size_t)B * n2 * 128);
  unsigned short* wt1l = wt1h + (size_t)NB * 128 * 256;
  unsigned short* wt2h = wt1l + (size_t)NB * 128 * 256;
  unsigned short* wt2l = wt2h + (size_t)NB * 128 * 256;
  unsigned short* fragx = wt2l + (size_t)NB * 128 * 256;   // B*(n1/16)*64*8
  unsigned short* fragn = fragx + (size_t)B * (n1 / 16) * 512;  // B*(n2/16)*64*8
  unsigned short* f1h = fragn + (size_t)B * (n2 / 16) * 512;
  unsigned short* f1l = f1h + 16384;
  unsigned short* f2h = f1l + 16384;
  unsigned short* f2l = f2h + 16384;

  k_wt<<<dim3(NB * 32), 256, 0, stream>>>(u1wc, u1wn, wt1h, wt1l);
  k_wt<<<dim3(NB * 32), 256, 0, stream>>>(u2wc, u2wn, wt2h, wt2l);
  k_wtf<<<dim3(64), 256, 0, stream>>>(fw1, f1h, f1l);
  k_wtf<<<dim3(64), 256, 0, stream>>>(fw2, f2h, f2l);

  k_transpose_in<<<dim3((B * n1 + 255) / 256), 256, 0, stream>>>(xyz, x, n1);
  k_frag<<<dim3(B * (n1 / 16) * 64 / 256), 256, 0, stream>>>(x, fragx, n1);
  k_knn2<<<dim3(n1 / 32, B), 256, 0, stream>>>(x, x, fragx, idx1, n1, n1);
  k_featnet2<<<dim3(n1 / 8, B), 256, 0, stream>>>(x, idx1, fw0, f1h, f1l, f2h, f2l, A, n1);
  for (int i = 0; i < NB; i++) {
    const float* pin = (i & 1) ? Bb : A;
    float* pout = (i & 1) ? A : Bb;
    k_conv<<<dim3((n1 / 32) * B), 256, 0, stream>>>(
        pin, pout, idx1, wt1h + (size_t)i * 128 * 256, wt1l + (size_t)i * 128 * 256, n1);
  }
  // block 11 input lives in Bb (i=11 odd: read Bb, write A); stage-1 final points in A
  k_unpool<<<dim3(n1 / 4, B), 256, 0, stream>>>(Bb, idx1, x, u1uc, u1un, nxz, n1, 0);
  k_frag<<<dim3(B * (n2 / 16) * 64 / 256), 256, 0, stream>>>(nxz, fragn, n2);
  k_knn2<<<dim3(n2 / 32, B), 256, 0, stream>>>(nxz, x, fragx, idx2g, n2, n1);
  k_meangather<<<dim3((B * n2 * 64 + 255) / 256), 256, 0, stream>>>(A, idx2g, Bb, n2, n1);
  k_knn2<<<dim3(n2 / 32, B), 256, 0, stream>>>(nxz, nxz, fragn, idx2s, n2, n2);
  for (int i = 0; i < NB; i++) {
    const float* pin = (i & 1) ? A : Bb;
    float* pout = (i & 1) ? Bb : A;
    k_conv64<<<dim3((n2 / 64) * B), 256, 0, stream>>>(
        pin, pout, idx2s, wt2h + (size_t)i * 128 * 256, wt2l + (size_t)i * 128 * 256, n2);
  }
  // block 11 input lives in A (i=11 odd: read A, write Bb); write d_out transposed
  k_unpool<<<dim3(n2 / 4, B), 256, 0, stream>>>(A, idx2s, nxz, u2uc, u2un, out, n2, 1);
}

// Round 14
// 1080.879 us; speedup vs baseline: 1.0360x; 1.0360x over previous
//
#include <hip/hip_runtime.h>
#include <hip/hip_bf16.h>

#define NB 12

typedef __attribute__((ext_vector_type(8))) short bf16x8;
typedef __attribute__((ext_vector_type(4))) float f32x4;

#define MFMA16(a, b, c) __builtin_amdgcn_mfma_f32_16x16x32_bf16(a, b, c, 0, 0, 0)

__device__ __forceinline__ unsigned short bf16r(float f) {
  unsigned int u = __float_as_uint(f);
  return (unsigned short)((u + 0x7fffu + ((u >> 16) & 1u)) >> 16);
}

__device__ __forceinline__ float bf2f(unsigned short h) {
  return __uint_as_float(((unsigned int)h) << 16);
}

// order-preserving fp32 <-> u32 (for LDS atomicMin gate); works for +/-
__device__ __forceinline__ unsigned int fenc(float f) {
  unsigned int u = __float_as_uint(f);
  return (u >> 31) ? ~u : (u | 0x80000000u);
}
__device__ __forceinline__ float fdec(unsigned int e) {
  unsigned int u = (e >> 31) ? (e & 0x7FFFFFFFu) : ~e;
  return __uint_as_float(u);
}

__device__ __forceinline__ float4 relu4(float4 v) {
  v.x = fmaxf(v.x, 0.f); v.y = fmaxf(v.y, 0.f);
  v.z = fmaxf(v.z, 0.f); v.w = fmaxf(v.w, 0.f);
  return v;
}

// packed RNE f32x2 -> bf16x2 (v_cvt_pk_bf16_f32)
__device__ __forceinline__ unsigned int pkbf(float x, float y) {
  __hip_bfloat162 h = __float22bfloat162_rn(make_float2(x, y));
  return *reinterpret_cast<unsigned int*>(&h);
}

// split fp32 pair-of-float4 into hi/lo bf16x8 via cvt_pk (hi=RNE, lo=RNE(residual))
__device__ __forceinline__ void split8(float4 a, float4 b, bf16x8* ph, bf16x8* pl) {
  unsigned int h01 = pkbf(a.x, a.y), h23 = pkbf(a.z, a.w);
  unsigned int h45 = pkbf(b.x, b.y), h67 = pkbf(b.z, b.w);
  float r0 = a.x - __uint_as_float(h01 << 16);
  float r1 = a.y - __uint_as_float(h01 & 0xFFFF0000u);
  float r2 = a.z - __uint_as_float(h23 << 16);
  float r3 = a.w - __uint_as_float(h23 & 0xFFFF0000u);
  float r4 = b.x - __uint_as_float(h45 << 16);
  float r5 = b.y - __uint_as_float(h45 & 0xFFFF0000u);
  float r6 = b.z - __uint_as_float(h67 << 16);
  float r7 = b.w - __uint_as_float(h67 & 0xFFFF0000u);
  uint4 H = make_uint4(h01, h23, h45, h67);
  uint4 L = make_uint4(pkbf(r0, r1), pkbf(r2, r3), pkbf(r4, r5), pkbf(r6, r7));
  *ph = *reinterpret_cast<bf16x8*>(&H);
  *pl = *reinterpret_cast<bf16x8*>(&L);
}

// xyz (b,3,n) -> x (b,n,3)
__global__ __launch_bounds__(256) void k_transpose_in(
    const float* __restrict__ xyz, float* __restrict__ x, int n) {
  int gid = blockIdx.x * 256 + threadIdx.x;
  if (gid >= 4 * n) return;
  int b = gid / n, i = gid % n;
  const float* src = xyz + (size_t)b * 3 * n;
  float* dst = x + (size_t)gid * 3;
  dst[0] = src[i];
  dst[1] = src[n + i];
  dst[2] = src[2 * n + i];
}

// weight prep hi/lo via LDS tile transpose (coalesced both sides):
// wt[i][e][d] = d<128 ? wc[i][d][e] : wn[i][d-128][e].
__global__ __launch_bounds__(256) void k_wt(
    const float* __restrict__ wc, const float* __restrict__ wn,
    unsigned short* __restrict__ wth, unsigned short* __restrict__ wtl) {
  __shared__ float tile[32][33];
  int bid = blockIdx.x;
  int et = bid & 3, dt = (bid >> 2) & 7, i = bid >> 5;
  int d0 = dt * 32, e0 = et * 32;
  int t = threadIdx.x;
  int el = t & 31, dg = t >> 5;
  const float* src = (d0 < 128) ? (wc + (size_t)i * 16384 + (size_t)d0 * 128)
                                : (wn + (size_t)i * 16384 + (size_t)(d0 - 128) * 128);
#pragma unroll
  for (int u = 0; u < 4; u++) {
    int dl = dg * 4 + u;
    tile[dl][el] = src[(size_t)dl * 128 + e0 + el];
  }
  __syncthreads();
  int dl = t & 31, eg = t >> 5;
#pragma unroll
  for (int u = 0; u < 4; u++) {
    int el2 = eg * 4 + u;
    float v = tile[dl][el2];
    unsigned short h = bf16r(v);
    size_t o = (size_t)i * 32768 + (size_t)(e0 + el2) * 256 + d0 + dl;
    wth[o] = h;
    wtl[o] = bf16r(v - bf2f(h));
  }
}

// featnet weight prep: wt[e][d] = w[d][e] hi/lo (w is [128][128])
__global__ __launch_bounds__(256) void k_wtf(
    const float* __restrict__ w, unsigned short* __restrict__ wh,
    unsigned short* __restrict__ wl) {
  int tid = blockIdx.x * 256 + threadIdx.x;  // 16384
  int e = tid >> 7, d = tid & 127;
  float v = w[d * 128 + e];
  unsigned short h = bf16r(v);
  wh[tid] = h;
  wl[tid] = bf16r(v - bf2f(h));
}

// A-fragment prep for MFMA kNN: per 16-ref tile, per lane (ref=lane&15, kg=lane>>4)
// K-slot layout (K=32): k0..2=Rh, k3..5=Rl, k6..8=Rh, k9=rrh, k10=rrl, rest 0.
__global__ __launch_bounds__(256) void k_frag(
    const float* __restrict__ pts, unsigned short* __restrict__ frag, int n) {
  int gid = blockIdx.x * 256 + threadIdx.x;
  int ntiles = n >> 4;
  if (gid >= 4 * ntiles * 64) return;
  int lane = gid & 63;
  int bt = gid >> 6;
  int b = bt / ntiles, tile = bt % ntiles;
  int rin = lane & 15, kg = lane >> 4;
  const float* p = pts + ((size_t)b * n + tile * 16 + rin) * 3;
  float px = p[0], py = p[1], pz = p[2];
  float rr = px * px + py * py + pz * pz;
  unsigned short h0 = bf16r(px), h1 = bf16r(py), h2 = bf16r(pz);
  unsigned short l0 = bf16r(px - bf2f(h0));
  unsigned short l1 = bf16r(py - bf2f(h1));
  unsigned short l2 = bf16r(pz - bf2f(h2));
  unsigned short rh = bf16r(rr), rl = bf16r(rr - bf2f(rh));
  bf16x8 f = (bf16x8)0;
  if (kg == 0) {
    f[0] = (short)h0; f[1] = (short)h1; f[2] = (short)h2;
    f[3] = (short)l0; f[4] = (short)l1; f[5] = (short)l2;
    f[6] = (short)h0; f[7] = (short)h1;
  } else if (kg == 1) {
    f[0] = (short)h2; f[1] = (short)rh; f[2] = (short)rl;
  }
  *(bf16x8*)(frag + (size_t)gid * 8) = f;
}

#define LCAS(A, B)                                                        \
  {                                                                       \
    bool sw_ = (dist[B] < dist[A]) ||                                     \
               (dist[B] == dist[A] && ind[B] < ind[A]);                   \
    float td_ = sw_ ? dist[A] : dist[B];                                  \
    int ti_ = sw_ ? ind[A] : ind[B];                                      \
    dist[A] = sw_ ? dist[B] : dist[A];                                    \
    ind[A] = sw_ ? ind[B] : ind[A];                                      \
    dist[B] = td_; ind[B] = ti_;                                          \
  }

// MFMA kNN, two-stage, 2-way ref split, SHARED cross-wave gate (R12-proven):
// block = 32 queries; wave w: query group g=w&1 (16 q), ref half z=w>>1.
// Gate refreshed once per 16-tile chunk (R13's 4-tile refresh regressed).
__global__ __launch_bounds__(256) void k_knn2(
    const float* __restrict__ Q, const float* __restrict__ Rpts,
    const unsigned short* __restrict__ frag,
    int* __restrict__ idx, int M, int N) {
  __shared__ unsigned short chunkbuf[32 * 512];  // 32 tiles * 1024 B = 32 KB
  __shared__ float smd[4][16][8];
  __shared__ int smi[4][16][8];
  __shared__ unsigned int qgate[32];
  int b = blockIdx.y;
  int t = threadIdx.x;
  int w = t >> 6, lane = t & 63;
  int col = lane & 15, kg = lane >> 4;
  int qg = w & 1, zh = w >> 1;
  int q = blockIdx.x * 32 + qg * 16 + col;
  if (t < 32) qgate[t] = fenc(3.4e38f);
  const float* qp = Q + ((size_t)b * M + q) * 3;
  float qx = qp[0], qy = qp[1], qz = qp[2];
  float qq = qx * qx + qy * qy + qz * qz;
  float m2x = -2.f * qx, m2y = -2.f * qy, m2z = -2.f * qz;
  unsigned short h0 = bf16r(m2x), h1 = bf16r(m2y), h2 = bf16r(m2z);
  unsigned short l0 = bf16r(m2x - bf2f(h0));
  unsigned short l1 = bf16r(m2y - bf2f(h1));
  unsigned short l2 = bf16r(m2z - bf2f(h2));
  bf16x8 bfrag = (bf16x8)0;
  if (kg == 0) {
    bfrag[0] = (short)h0; bfrag[1] = (short)h1; bfrag[2] = (short)h2;
    bfrag[3] = (short)h0; bfrag[4] = (short)h1; bfrag[5] = (short)h2;
    bfrag[6] = (short)l0; bfrag[7] = (short)l1;
  } else if (kg == 1) {
    bfrag[0] = (short)l2;
    bfrag[1] = (short)0x3F80; bfrag[2] = (short)0x3F80;  // 1.0 bf16
  }
  float dist[8];
  int ind[8];
#pragma unroll
  for (int j = 0; j < 8; j++) { dist[j] = 3.4e38f; ind[j] = 0; }
  float g8 = 3.4e38f;  // shared-gate snapshot (stale = looser = safe)
  int ntiles = N >> 4;
  int half = ntiles >> 1;
  const unsigned short* fb = frag + (size_t)b * ntiles * 512;
  for (int c = 0; c < half; c += 16) {
    __syncthreads();
    {
      const float4* src = (const float4*)fb;
      float4* dst = (float4*)chunkbuf;
      for (int i = t; i < 1024; i += 256) {
        dst[i] = src[(size_t)c * 64 + i];
        dst[1024 + i] = src[(size_t)(half + c) * 64 + i];
      }
    }
    __syncthreads();
    int lbase = zh * 16;
    int cbase = (zh * half + c) * 16;
    for (int tl = 0; tl < 16; tl++) {
      bf16x8 af = *(const bf16x8*)(&chunkbuf[((lbase + tl) * 64 + lane) * 8]);
      f32x4 z = (f32x4){0.f, 0.f, 0.f, 0.f};
      f32x4 sc = MFMA16(af, bfrag, z);
      float g = fminf(dist[7], g8);
      unsigned int m = 0;
      m |= (sc[0] < g) ? 1u : 0u;
      m |= (sc[1] < g) ? 2u : 0u;
      m |= (sc[2] < g) ? 4u : 0u;
      m |= (sc[3] < g) ? 8u : 0u;
#pragma unroll 1
      for (int it = 0; it < 4; ++it) {
        if (!__any(m != 0u)) break;
        if (m != 0u) {
          int r = (int)__builtin_ctz(m);
          m &= m - 1u;
          float dd = (r & 2) ? ((r & 1) ? sc[3] : sc[2])
                             : ((r & 1) ? sc[1] : sc[0]);
          int ii = cbase + tl * 16 + kg * 4 + r;
#pragma unroll
          for (int j = 0; j < 8; j++) {  // bubble insert; self-guards if dd >= dist[7]
            bool sw = dd < dist[j];
            float td = sw ? dist[j] : dd;
            int ti = sw ? ind[j] : ii;
            dist[j] = sw ? dd : dist[j];
            ind[j] = sw ? ii : ind[j];
            dd = td; ii = ti;
          }
        }
      }
    }
    // publish own running 8th (min over the 4 kg-lanes) and fetch shared gate
    float t1 = fminf(dist[7], __shfl_xor(dist[7], 16, 64));
    float own8 = fminf(t1, __shfl_xor(t1, 32, 64));
    if (kg == 0) atomicMin(&qgate[qg * 16 + col], fenc(own8));
    g8 = fminf(own8, fdec(qgate[qg * 16 + col]));
  }
  // exact fp32 rescore of this lane's 8 candidates + stable lex resort
  {
    const float* Rb2 = Rpts + (size_t)b * N * 3;
    float nd[8];
#pragma unroll
    for (int j = 0; j < 8; j++) {
      int ii = ind[j];
      float rx = Rb2[(size_t)ii * 3 + 0];
      float ry = Rb2[(size_t)ii * 3 + 1];
      float rz = Rb2[(size_t)ii * 3 + 2];
      float rr = rx * rx + ry * ry + rz * rz;
      nd[j] = qq + rr - 2.0f * (qx * rx + qy * ry + qz * rz);
    }
    float sd[8]; int si[8];
#pragma unroll
    for (int j = 0; j < 8; j++) { sd[j] = 3.4e38f; si[j] = 0x7fffffff; }
#pragma unroll
    for (int j = 0; j < 8; j++) {
      float dd = nd[j]; int ii = ind[j];
#pragma unroll
      for (int p = 0; p < 8; p++) {
        bool sw = (dd < sd[p]) || (dd == sd[p] && ii < si[p]);
        float td = sw ? sd[p] : dd;
        int ti = sw ? si[p] : ii;
        sd[p] = sw ? dd : sd[p];
        si[p] = sw ? ii : si[p];
        dd = td; ii = ti;
      }
    }
#pragma unroll
    for (int j = 0; j < 8; j++) { dist[j] = sd[j]; ind[j] = si[j]; }
  }
  // merge 4 sorted kg-lists of each query: levels xor 16, 32
#pragma unroll
  for (int lev = 0; lev < 2; lev++) {
    int D = 16 << lev;
    float od[8]; int oi[8];
#pragma unroll
    for (int j = 0; j < 8; j++) {
      od[j] = __shfl_xor(dist[j], D, 64);
      oi[j] = __shfl_xor(ind[j], D, 64);
    }
#pragma unroll
    for (int j = 0; j < 8; j++) {  // half-cleaner: keep 8 smallest (lex)
      float bd = od[7 - j]; int bi = oi[7 - j];
      bool take = (bd < dist[j]) || (bd == dist[j] && bi < ind[j]);
      dist[j] = take ? bd : dist[j];
      ind[j] = take ? bi : ind[j];
    }
    LCAS(0, 4) LCAS(1, 5) LCAS(2, 6) LCAS(3, 7)
    LCAS(0, 2) LCAS(1, 3) LCAS(4, 6) LCAS(5, 7)
    LCAS(0, 1) LCAS(2, 3) LCAS(4, 5) LCAS(6, 7)
  }
  if (kg == 0) {
#pragma unroll
    for (int j = 0; j < 8; j++) { smd[w][col][j] = dist[j]; smi[w][col][j] = ind[j]; }
  }
  __syncthreads();
  // cross-half rank merge: thread (tq, jj); query group g = tq>>4 -> lists g, g+2
  int tq = t >> 3, jj = t & 7;
  int g = tq >> 4, qcol = tq & 15;
  float d0 = smd[g][qcol][jj];     int i0 = smi[g][qcol][jj];
  float d1 = smd[g + 2][qcol][jj]; int i1 = smi[g + 2][qcol][jj];
  int r0 = jj, r1 = jj;
#pragma unroll
  for (int p = 0; p < 8; p++) {
    float dp = smd[g + 2][qcol][p]; int ip = smi[g + 2][qcol][p];
    r0 += (dp < d0 || (dp == d0 && ip < i0)) ? 1 : 0;
    float dq = smd[g][qcol][p];     int iq = smi[g][qcol][p];
    r1 += (dq < d1 || (dq == d1 && iq < i1)) ? 1 : 0;
  }
  int* o = idx + ((size_t)b * M + blockIdx.x * 32 + tq) * 8;
  if (r0 < 8) o[r0] = i0;
  if (r1 < 8) o[r1] = i1;
}

// feature_net via split-bf16 MFMA: 8 queries/block -> 64 rows (q*8+j).
__global__ __launch_bounds__(256) void k_featnet2(
    const float* __restrict__ x, const int* __restrict__ idx,
    const float* __restrict__ w0,
    const unsigned short* __restrict__ w1h, const unsigned short* __restrict__ w1l,
    const unsigned short* __restrict__ w2h, const unsigned short* __restrict__ w2l,
    float* __restrict__ out, int n) {
  __shared__ unsigned short Xh[64 * 128];  // 16 KB
  __shared__ unsigned short Xl[64 * 128];  // 16 KB
  __shared__ float F[64 * 128];            // 32 KB
  int b = blockIdx.y, t = threadIdx.x;
  int q0 = blockIdx.x * 8;
  {
    int row = t >> 2, seg = t & 3;
    int qi = row >> 3, j = row & 7;
    size_t qb = (size_t)b * n + q0 + qi;
    const float* qp = x + qb * 3;
    int nb = idx[qb * 8 + j];
    const float* pp = x + ((size_t)b * n + nb) * 3;
    float r0 = pp[0] - qp[0], r1 = pp[1] - qp[1], r2 = pp[2] - qp[2];
#pragma unroll
    for (int u = 0; u < 4; u++) {
      int cc = seg * 32 + u * 8;
      float h[8];
#pragma unroll
      for (int v = 0; v < 8; v++) {
        int c = cc + v;
        h[v] = fmaxf(fmaf(r0, w0[c], fmaf(r1, w0[128 + c], r2 * w0[256 + c])), 0.f);
      }
      float4 a = make_float4(h[0], h[1], h[2], h[3]);
      float4 bb = make_float4(h[4], h[5], h[6], h[7]);
      int lc = seg * 4 + u;
      int ph = row * 128 + ((lc ^ (row & 7)) * 8);
      split8(a, bb, (bf16x8*)&Xh[ph], (bf16x8*)&Xl[ph]);
    }
  }
  __syncthreads();
  int w = t >> 6, lane = t & 63;
  int lo = lane & 15, hi = lane >> 4;
  f32x4 acc[4][2];
#pragma unroll
  for (int mt = 0; mt < 4; mt++)
#pragma unroll
    for (int nt = 0; nt < 2; nt++) acc[mt][nt] = (f32x4){0.f, 0.f, 0.f, 0.f};
  {
    const unsigned short* wbh = w1h + ((size_t)(w * 32 + lo) * 128 + hi * 8);
    const unsigned short* wbl = w1l + ((size_t)(w * 32 + lo) * 128 + hi * 8);
#pragma unroll
    for (int kk = 0; kk < 4; kk++) {
      bf16x8 ah[4], al[4];
#pragma unroll
      for (int mt = 0; mt < 4; mt++) {
        int row = mt * 16 + lo;
        int off = row * 128 + (((4 * kk + hi) ^ (row & 7)) * 8);
        ah[mt] = *(const bf16x8*)(&Xh[off]);
        al[mt] = *(const bf16x8*)(&Xl[off]);
      }
      bf16x8 bh0 = *(const bf16x8*)(wbh + kk * 32);
      bf16x8 bh1 = *(const bf16x8*)(wbh + 16 * 128 + kk * 32);
      bf16x8 bl0 = *(const bf16x8*)(wbl + kk * 32);
      bf16x8 bl1 = *(const bf16x8*)(wbl + 16 * 128 + kk * 32);
#pragma unroll
      for (int mt = 0; mt < 4; mt++) {
        acc[mt][0] = MFMA16(ah[mt], bh0, acc[mt][0]);
        acc[mt][0] = MFMA16(ah[mt], bl0, acc[mt][0]);
        acc[mt][0] = MFMA16(al[mt], bh0, acc[mt][0]);
        acc[mt][1] = MFMA16(ah[mt], bh1, acc[mt][1]);
        acc[mt][1] = MFMA16(ah[mt], bl1, acc[mt][1]);
        acc[mt][1] = MFMA16(al[mt], bh1, acc[mt][1]);
      }
    }
  }
#pragma unroll
  for (int mt = 0; mt < 4; mt++)
#pragma unroll
    for (int nt = 0; nt < 2; nt++) {
      int colc = w * 32 + nt * 16 + lo;
      int chunk = colc >> 2, cr = colc & 3;
#pragma unroll
      for (int r = 0; r < 4; r++) {
        int row = mt * 16 + hi * 4 + r;
        F[row * 128 + ((chunk ^ ((row & 7) << 2)) << 2) + cr] = acc[mt][nt][r];
      }
    }
  __syncthreads();
  {
    int row = t >> 2, seg = t & 3;
#pragma unroll
    for (int u = 0; u < 4; u++) {
      int cc = (seg * 32 + u * 8) >> 2;  // even chunk index
      int pc = cc ^ ((row & 7) << 2);
      float4 a = *(const float4*)(&F[row * 128 + pc * 4]);
      float4 bb = *(const float4*)(&F[row * 128 + (pc + 1) * 4]);
      a = relu4(a); bb = relu4(bb);
      int lc = seg * 4 + u;
      int ph = row * 128 + ((lc ^ (row & 7)) * 8);
      split8(a, bb, (bf16x8*)&Xh[ph], (bf16x8*)&Xl[ph]);
    }
  }
  __syncthreads();
#pragma unroll
  for (int mt = 0; mt < 4; mt++)
#pragma unroll
    for (int nt = 0; nt < 2; nt++) acc[mt][nt] = (f32x4){0.f, 0.f, 0.f, 0.f};
  {
    const unsigned short* wbh = w2h + ((size_t)(w * 32 + lo) * 128 + hi * 8);
    const unsigned short* wbl = w2l + ((size_t)(w * 32 + lo) * 128 + hi * 8);
#pragma unroll
    for (int kk = 0; kk < 4; kk++) {
      bf16x8 ah[4], al[4];
#pragma unroll
      for (int mt = 0; mt < 4; mt++) {
        int row = mt * 16 + lo;
        int off = row * 128 + (((4 * kk + hi) ^ (row & 7)) * 8);
        ah[mt] = *(const bf16x8*)(&Xh[off]);
        al[mt] = *(const bf16x8*)(&Xl[off]);
      }
      bf16x8 bh0 = *(const bf16x8*)(wbh + kk * 32);
      bf16x8 bh1 = *(const bf16x8*)(wbh + 16 * 128 + kk * 32);
      bf16x8 bl0 = *(const bf16x8*)(wbl + kk * 32);
      bf16x8 bl1 = *(const bf16x8*)(wbl + 16 * 128 + kk * 32);
#pragma unroll
      for (int mt = 0; mt < 4; mt++) {
        acc[mt][0] = MFMA16(ah[mt], bh0, acc[mt][0]);
        acc[mt][0] = MFMA16(ah[mt], bl0, acc[mt][0]);
        acc[mt][0] = MFMA16(al[mt], bh0, acc[mt][0]);
        acc[mt][1] = MFMA16(ah[mt], bh1, acc[mt][1]);
        acc[mt][1] = MFMA16(ah[mt], bl1, acc[mt][1]);
        acc[mt][1] = MFMA16(al[mt], bh1, acc[mt][1]);
      }
    }
  }
#pragma unroll
  for (int mt = 0; mt < 4; mt++)
#pragma unroll
    for (int nt = 0; nt < 2; nt++) {
      float m = fmaxf(fmaxf(acc[mt][nt][0], acc[mt][nt][1]),
                      fmaxf(acc[mt][nt][2], acc[mt][nt][3]));
      float o = fmaxf(m, __shfl_xor(m, 16, 64));
      if ((hi & 1) == 0) {
        int q = q0 + mt * 2 + (hi >> 1);
        out[((size_t)b * n + q) * 128 + w * 32 + nt * 16 + lo] = fmaxf(o, 0.f);
      }
    }
}

// residual graph-conv via split-precision bf16 MFMA, BM=32, XCD-bound 1D grid:
// batch b owns XCDs {2b,2b+1} so each XCD's L2 caches only one batch's P rows.
__global__ __launch_bounds__(256) void k_conv(
    const float* __restrict__ Pin, float* __restrict__ Pout,
    const int* __restrict__ idx, const unsigned short* __restrict__ wth,
    const unsigned short* __restrict__ wtl, int n) {
  __shared__ unsigned short Xh[32 * 256];  // 16 KB
  __shared__ unsigned short Xl[32 * 256];  // 16 KB
  int t = threadIdx.x;
  int fid = blockIdx.x;
  int x8 = fid & 7;
  int b = x8 >> 1;
  int rblk = ((fid >> 3) * 2 + (x8 & 1)) * 32;
  {
    int row = t >> 3, seg = t & 7;      // 32 rows x 8 segs; seg covers 16 floats
    size_t rb = (size_t)b * n + rblk + row;
    const float4* src = (const float4*)(Pin + rb * 128 + seg * 16);
    float4 cv[4];
#pragma unroll
    for (int u = 0; u < 4; u++) cv[u] = relu4(src[u]);
    const int* ip = idx + rb * 8;
    float4 ns[4];
#pragma unroll
    for (int u = 0; u < 4; u++) ns[u] = make_float4(0.f, 0.f, 0.f, 0.f);
#pragma unroll
    for (int j = 0; j < 8; j++) {
      const float4* s2 = (const float4*)(Pin + ((size_t)b * n + ip[j]) * 128 + seg * 16);
#pragma unroll
      for (int u = 0; u < 4; u++) {
        float4 v = relu4(s2[u]);
        ns[u].x += v.x; ns[u].y += v.y; ns[u].z += v.z; ns[u].w += v.w;
      }
    }
#pragma unroll
    for (int u = 0; u < 2; u++) {
      int lc = seg * 2 + u;                         // center chunks 0..15
      int ph = (row * 256 + ((lc ^ (row & 7)) * 8));
      split8(cv[2 * u], cv[2 * u + 1], (bf16x8*)&Xh[ph], (bf16x8*)&Xl[ph]);
      int lc2 = 16 + seg * 2 + u;                   // neighbor-sum chunks 16..31
      int ph2 = (row * 256 + ((lc2 ^ (row & 7)) * 8));
      split8(ns[2 * u], ns[2 * u + 1], (bf16x8*)&Xh[ph2], (bf16x8*)&Xl[ph2]);
    }
  }
  __syncthreads();
  int w = t >> 6, lane = t & 63;
  int lo = lane & 15, hi = lane >> 4;
  f32x4 acc[2][2];
#pragma unroll
  for (int mt = 0; mt < 2; mt++)
#pragma unroll
    for (int nt = 0; nt < 2; nt++) acc[mt][nt] = (f32x4){0.f, 0.f, 0.f, 0.f};
  const unsigned short* wbh = wth + ((size_t)(w * 32 + lo) * 256 + hi * 8);
  const unsigned short* wbl = wtl + ((size_t)(w * 32 + lo) * 256 + hi * 8);
#pragma unroll
  for (int kk = 0; kk < 8; kk++) {
    bf16x8 ah[2], al[2];
#pragma unroll
    for (int mt = 0; mt < 2; mt++) {
      int row = mt * 16 + lo;
      int off = row * 256 + (((4 * kk + hi) ^ (row & 7)) * 8);
      ah[mt] = *(const bf16x8*)(&Xh[off]);
      al[mt] = *(const bf16x8*)(&Xl[off]);
    }
    bf16x8 bh0 = *(const bf16x8*)(wbh + kk * 32);
    bf16x8 bh1 = *(const bf16x8*)(wbh + 4096 + kk * 32);
    bf16x8 bl0 = *(const bf16x8*)(wbl + kk * 32);
    bf16x8 bl1 = *(const bf16x8*)(wbl + 4096 + kk * 32);
#pragma unroll
    for (int mt = 0; mt < 2; mt++) {
      acc[mt][0] = MFMA16(ah[mt], bh0, acc[mt][0]);
      acc[mt][0] = MFMA16(ah[mt], bl0, acc[mt][0]);
      acc[mt][0] = MFMA16(al[mt], bh0, acc[mt][0]);
      acc[mt][1] = MFMA16(ah[mt], bh1, acc[mt][1]);
      acc[mt][1] = MFMA16(ah[mt], bl1, acc[mt][1]);
      acc[mt][1] = MFMA16(al[mt], bh1, acc[mt][1]);
    }
  }
  const float inv9 = 1.0f / 9.0f;
#pragma unroll
  for (int mt = 0; mt < 2; mt++)
#pragma unroll
    for (int nt = 0; nt < 2; nt++) {
      int col = w * 32 + nt * 16 + lo;
#pragma unroll
      for (int r = 0; r < 4; r++) {
        int row = rblk + mt * 16 + hi * 4 + r;
        size_t off = ((size_t)b * n + row) * 128 + col;
        Pout[off] = fmaf(acc[mt][nt][r], inv9, Pin[off]);
      }
    }
}

// unpool: off6 = (relu(P)@uc + ns@un)/9; new[b][r*n+i][j] = xin[b][i][j] + off6[j*2+r]
__global__ __launch_bounds__(256) void k_unpool(
    const float* __restrict__ Pin, const int* __restrict__ idx,
    const float* __restrict__ xin,
    const float* __restrict__ uc, const float* __restrict__ un,
    float* __restrict__ out, int n, int transposed) {
  int b = blockIdx.y;
  int wv = threadIdx.x >> 6, lane = threadIdx.x & 63;
  int i = blockIdx.x * 4 + wv;
  if (i >= n) return;
  size_t rb = (size_t)b * n + i;
  const float* p0 = Pin + rb * 128;
  float pd0 = fmaxf(p0[lane], 0.f), pd1 = fmaxf(p0[lane + 64], 0.f);
  const int* ip = idx + rb * 8;
  float ns0 = 0.f, ns1 = 0.f;
#pragma unroll
  for (int j = 0; j < 8; j++) {
    const float* pj = Pin + ((size_t)b * n + ip[j]) * 128;
    ns0 += fmaxf(pj[lane], 0.f);
    ns1 += fmaxf(pj[lane + 64], 0.f);
  }
  float acc[6];
#pragma unroll
  for (int o = 0; o < 6; o++)
    acc[o] = pd0 * uc[lane * 6 + o] + pd1 * uc[(lane + 64) * 6 + o] +
             ns0 * un[lane * 6 + o] + ns1 * un[(lane + 64) * 6 + o];
#pragma unroll
  for (int s = 32; s > 0; s >>= 1) {
#pragma unroll
    for (int o = 0; o < 6; o++) acc[o] += __shfl_xor(acc[o], s, 64);
  }
  if (lane < 6) {
    int j = lane >> 1, r = lane & 1;
    float v = xin[rb * 3 + j] + acc[lane] * (1.0f / 9.0f);
    if (transposed)
      out[(size_t)b * 6 * n + (size_t)j * 2 * n + (size_t)r * n + i] = v;
    else
      out[((size_t)b * 2 * n + (size_t)r * n + i) * 3 + j] = v;
  }
}

// points2[b][m] = mean_j Pin[b][idx[b][m][j]]
__global__ __launch_bounds__(256) void k_meangather(
    const float* __restrict__ Pin, const int* __restrict__ idx,
    float* __restrict__ Pout, int M, int nsrc) {
  int gid = blockIdx.x * 256 + threadIdx.x;
  int row = gid >> 6, lane = gid & 63;
  if (row >= 4 * M) return;
  int b = row / M;
  const int* ip = idx + (size_t)row * 8;
  float s0 = 0.f, s1 = 0.f;
#pragma unroll
  for (int j = 0; j < 8; j++) {
    const float* p = Pin + ((size_t)b * nsrc + ip[j]) * 128;
    s0 += p[lane];
    s1 += p[lane + 64];
  }
  Pout[(size_t)row * 128 + lane] = s0 * 0.125f;
  Pout[(size_t)row * 128 + lane + 64] = s1 * 0.125f;
}

extern "C" void kernel_launch(void* const* d_in, const int* in_sizes, int n_in,
                              void* d_out, int out_size, void* d_ws, size_t ws_size,
                              hipStream_t stream) {
  const float* xyz = (const float*)d_in[0];
  const float* fw0 = (const float*)d_in[1];
  const float* fw1 = (const float*)d_in[2];
  const float* fw2 = (const float*)d_in[3];
  const float* u1wc = (const float*)d_in[4];
  const float* u1wn = (const float*)d_in[5];
  const float* u1uc = (const float*)d_in[6];
  const float* u1un = (const float*)d_in[7];
  const float* u2wc = (const float*)d_in[8];
  const float* u2wn = (const float*)d_in[9];
  const float* u2uc = (const float*)d_in[10];
  const float* u2un = (const float*)d_in[11];
  float* out = (float*)d_out;

  const int n1 = 4096, n2 = 8192, B = 4;
  float* ws = (float*)d_ws;
  float* x = ws;                                  // B*n1*3
  float* nxz = x + (size_t)B * n1 * 3;            // B*n2*3
  int* idx1 = (int*)(nxz + (size_t)B * n2 * 3);   // B*n1*8
  int* idx2g = idx1 + (size_t)B * n1 * 8;         // B*n2*8
  int* idx2s = idx2g + (size_t)B * n2 * 8;        // B*n2*8
  float* A = (float*)(idx2s + (size_t)B * n2 * 8);
  float* Bb = A + (size_t)B * n2 * 128;
  unsigned short* wt1h = (unsigned short*)(Bb + (size_t)B * n2 * 128);
  unsigned short* wt1l = wt1h + (size_t)NB * 128 * 256;
  unsigned short* wt2h = wt1l + (size_t)NB * 128 * 256;
  unsigned short* wt2l = wt2h + (size_t)NB * 128 * 256;
  unsigned short* fragx = wt2l + (size_t)NB * 128 * 256;   // B*(n1/16)*64*8
  unsigned short* fragn = fragx + (size_t)B * (n1 / 16) * 512;  // B*(n2/16)*64*8
  unsigned short* f1h = fragn + (size_t)B * (n2 / 16) * 512;
  unsigned short* f1l = f1h + 16384;
  unsigned short* f2h = f1l + 16384;
  unsigned short* f2l = f2h + 16384;

  k_wt<<<dim3(NB * 32), 256, 0, stream>>>(u1wc, u1wn, wt1h, wt1l);
  k_wt<<<dim3(NB * 32), 256, 0, stream>>>(u2wc, u2wn, wt2h, wt2l);
  k_wtf<<<dim3(64), 256, 0, stream>>>(fw1, f1h, f1l);
  k_wtf<<<dim3(64), 256, 0, stream>>>(fw2, f2h, f2l);

  k_transpose_in<<<dim3((B * n1 + 255) / 256), 256, 0, stream>>>(xyz, x, n1);
  k_frag<<<dim3(B * (n1 / 16) * 64 / 256), 256, 0, stream>>>(x, fragx, n1);
  k_knn2<<<dim3(n1 / 32, B), 256, 0, stream>>>(x, x, fragx, idx1, n1, n1);
  k_featnet2<<<dim3(n1 / 8, B), 256, 0, stream>>>(x, idx1, fw0, f1h, f1l, f2h, f2l, A, n1);
  for (int i = 0; i < NB; i++) {
    const float* pin = (i & 1) ? Bb : A;
    float* pout = (i & 1) ? A : Bb;
    k_conv<<<dim3((n1 / 32) * B), 256, 0, stream>>>(
        pin, pout, idx1, wt1h + (size_t)i * 128 * 256, wt1l + (size_t)i * 128 * 256, n1);
  }
  // block 11 input lives in Bb (i=11 odd: read Bb, write A); stage-1 final points in A
  k_unpool<<<dim3(n1 / 4, B), 256, 0, stream>>>(Bb, idx1, x, u1uc, u1un, nxz, n1, 0);
  k_frag<<<dim3(B * (n2 / 16) * 64 / 256), 256, 0, stream>>>(nxz, fragn, n2);
  k_knn2<<<dim3(n2 / 32, B), 256, 0, stream>>>(nxz, x, fragx, idx2g, n2, n1);
  k_meangather<<<dim3((B * n2 * 64 + 255) / 256), 256, 0, stream>>>(A, idx2g, Bb, n2, n1);
  k_knn2<<<dim3(n2 / 32, B), 256, 0, stream>>>(nxz, nxz, fragn, idx2s, n2, n2);
  for (int i = 0; i < NB; i++) {
    const float* pin = (i & 1) ? A : Bb;
    float* pout = (i & 1) ? Bb : A;
    k_conv<<<dim3((n2 / 32) * B), 256, 0, stream>>>(
        pin, pout, idx2s, wt2h + (size_t)i * 128 * 256, wt2l + (size_t)i * 128 * 256, n2);
  }
  // block 11 input lives in A (i=11 odd: read A, write Bb); write d_out transposed
  k_unpool<<<dim3(n2 / 4, B), 256, 0, stream>>>(A, idx2s, nxz, u2uc, u2un, out, n2, 1);
}